// Round 1
// baseline (846.516 us; speedup 1.0000x reference)
//
#include <hip/hip_runtime.h>
#include <stdint.h>

#define NF 8192          // features per row
#define NR 8192          // rows
#define TPB 256          // threads per block
#define RPB 4            // rows per block
#define TGRID (NR / RPB) // 2048 blocks
#define KSEL 2867        // floor(0.35 * 8192)
#define CAND_CAP 2048
#define EQCAP 128

typedef float    floatx4 __attribute__((ext_vector_type(4)));
typedef uint32_t uintx4  __attribute__((ext_vector_type(4)));

// order-preserving float -> uint mapping (ascending)
__device__ __forceinline__ uint32_t f2s(float f) {
    uint32_t u = __float_as_uint(f);
    return u ^ ((uint32_t)((int32_t)u >> 31) | 0x80000000u);
}

__global__ __launch_bounds__(TPB) void boost_k(const float* __restrict__ dc,
                                               float* __restrict__ boost) {
    const int i = blockIdx.x * TPB + threadIdx.x;
    const float target = (float)KSEL / (float)NF; // 0.3499755859375, exact in f32
    boost[i] = expf(1.5f * (target - dc[i]));
}

__device__ __forceinline__ bool kept2(uint32_t u, uint32_t T, uint32_t col,
                                      bool keepall, uint32_t need,
                                      const uint32_t* eq) {
    if (u > T) return true;
    if (u != T) return false;
    if (keepall) return true;
    for (uint32_t i = 0; i < need; ++i)
        if (eq[i] == col) return true;
    return false;
}

// wave 0 only: suffix-scan 256 bins (x4 replicated), find bucket holding rank sh[1]
__device__ __forceinline__ void select_level(const uint32_t* hb, uint32_t* sh,
                                             int lane, int shift) {
    const uintx4* h4 = (const uintx4*)hb;
    uint32_t hh[4];
    uint32_t g = 0;
#pragma unroll
    for (int b = 0; b < 4; ++b) {
        const uintx4 q = h4[4 * lane + b]; // 4 replicas of bin 4*lane+b
        hh[b] = q.x + q.y + q.z + q.w;
        g += hh[b];
    }
    uint32_t inc = g;
#pragma unroll
    for (int off = 1; off < 64; off <<= 1) {
        const uint32_t o = __shfl_down(inc, off);
        if (lane + off < 64) inc += o;
    }
    const uint32_t kk = sh[1];
    const uint32_t above = inc - g; // elements in strictly higher bins
    if (above < kk && kk <= inc) {
        uint32_t c = above;
        const uint32_t oldp = sh[0];
#pragma unroll
        for (int b = 3; b >= 0; --b) {
            c += hh[b];
            if (c >= kk) {
                sh[0] = oldp | ((uint32_t)(4 * lane + b) << shift);
                sh[1] = kk - (c - hh[b]); // residual rank within bucket
                sh[2] = hh[b];            // bucket population
                break;
            }
        }
    }
}

__global__ __launch_bounds__(TPB, 6) void topk_k(const float* __restrict__ x,
                                                 const float* __restrict__ boost,
                                                 float* __restrict__ out,
                                                 uint32_t* __restrict__ partials) {
    // LDS: 8K hist (2 bufs x 256 bins x 4 replicas) + 8K cand + eq + sh ~= 16.6 KB
    __shared__ __align__(16) uint32_t hist[2][1024];
    __shared__ __align__(16) uint32_t cand[CAND_CAP];
    __shared__ uint32_t eq_i[EQCAP];
    __shared__ uint32_t sh[8]; // 0: prefix/T, 1: rank residual, 2: bucket pop, 3: cand cnt, 4: eq cnt

    const int t = threadIdx.x;
    const int lane = t & 63;
    const int wv = t >> 6;
    const int sub = t & 3;
    const uintx4 z4 = {0u, 0u, 0u, 0u};

    // boost is identical for every row: hoist into registers once per block
    floatx4 bf[8];
    {
        const floatx4* b4 = (const floatx4*)boost;
#pragma unroll
        for (int j = 0; j < 8; ++j) bf[j] = b4[j * TPB + t];
    }

    // both hist buffers clean at row start (invariant maintained by clears below)
    ((uintx4*)hist[0])[t] = z4;
    ((uintx4*)hist[1])[t] = z4;

    uint32_t cnt4[4] = {0, 0, 0, 0}; // nibble-packed per-column pos counts (8 cols/word)

    for (int r = 0; r < RPB; ++r) {
        const int row = blockIdx.x * RPB + r;
        const floatx4* x4 = (const floatx4*)(x + (size_t)row * NF);

        __syncthreads(); // prev-row epilogue done; hists clean
        if (t < 8) sh[t] = (t == 1) ? (uint32_t)KSEL : 0u;

        // stage: global -> regs; pass-1 histogram (top byte) from registers
        floatx4 v[8];
#pragma unroll
        for (int j = 0; j < 8; ++j)
            v[j] = __builtin_nontemporal_load(&x4[j * TPB + t]);
#pragma unroll
        for (int j = 0; j < 8; ++j) {
            atomicAdd(&hist[0][(f2s(v[j].x * bf[j].x) >> 24) * 4 + sub], 1u);
            atomicAdd(&hist[0][(f2s(v[j].y * bf[j].y) >> 24) * 4 + sub], 1u);
            atomicAdd(&hist[0][(f2s(v[j].z * bf[j].z) >> 24) * 4 + sub], 1u);
            atomicAdd(&hist[0][(f2s(v[j].w * bf[j].w) >> 24) * 4 + sub], 1u);
        }
        __syncthreads();

        if (wv == 0) select_level(hist[0], sh, lane, 24);
        __syncthreads();

        // compact the selected top-byte bucket (~0.9K keys) into cand[]
        const bool uc = (sh[2] <= (uint32_t)CAND_CAP);
        const uint32_t pfx0 = sh[0];
        if (uc) {
#pragma unroll
            for (int j = 0; j < 8; ++j) {
                uint32_t uu[4];
                uu[0] = f2s(v[j].x * bf[j].x);
                uu[1] = f2s(v[j].y * bf[j].y);
                uu[2] = f2s(v[j].z * bf[j].z);
                uu[3] = f2s(v[j].w * bf[j].w);
#pragma unroll
                for (int c = 0; c < 4; ++c) {
                    const bool m = (uu[c] & 0xFF000000u) == pfx0;
                    const unsigned long long mk = __ballot(m);
                    if (mk) { // wave-uniform
                        const int leader = __builtin_ctzll(mk);
                        uint32_t base = 0;
                        if (lane == leader)
                            base = atomicAdd(&sh[3], (uint32_t)__builtin_popcountll(mk));
                        base = __shfl(base, leader);
                        if (m)
                            cand[base + (uint32_t)__builtin_popcountll(
                                            mk & ((1ull << lane) - 1ull))] = uu[c];
                    }
                }
            }
        }
        __syncthreads();
        const uint32_t nc = sh[3];

        // 3 more radix levels over the compact list (fallback: over registers)
        for (int pass = 1; pass < 4; ++pass) {
            const int shift = 24 - 8 * pass;
            uint32_t* hb = hist[pass & 1];
            uint32_t* ho = hist[(pass & 1) ^ 1];
            ((uintx4*)ho)[t] = z4; // clear the other buffer (not read this phase)
            const uint32_t prefix = sh[0];
            const uint32_t himask = 0xFFFFFFFFu << (shift + 8);
            if (uc) {
                for (uint32_t i = t; i < nc; i += TPB) {
                    const uint32_t u = cand[i];
                    if ((u & himask) == prefix)
                        atomicAdd(&hb[((u >> shift) & 0xFFu) * 4 + sub], 1u);
                }
            } else {
#pragma unroll
                for (int j = 0; j < 8; ++j) {
                    uint32_t uu[4];
                    uu[0] = f2s(v[j].x * bf[j].x);
                    uu[1] = f2s(v[j].y * bf[j].y);
                    uu[2] = f2s(v[j].z * bf[j].z);
                    uu[3] = f2s(v[j].w * bf[j].w);
#pragma unroll
                    for (int c = 0; c < 4; ++c)
                        if ((uu[c] & himask) == prefix)
                            atomicAdd(&hb[((uu[c] >> shift) & 0xFFu) * 4 + sub], 1u);
                }
            }
            __syncthreads();
            if (wv == 0) select_level(hb, sh, lane, shift);
            __syncthreads();
        }
        // sh[0] = exact k-th largest key T; sh[1] = #ties to keep; sh[2] = #elements == T

        const uint32_t T = sh[0];
        const uint32_t need = sh[1];
        const uint32_t meq = sh[2];
        const bool keepall = (meq == need);
        const uint32_t needc = (need < (uint32_t)EQCAP) ? need : (uint32_t)EQCAP;

        if (!keepall) { // rare: duplicate keys at the threshold
#pragma unroll
            for (int j = 0; j < 8; ++j) {
                uint32_t uu[4];
                uu[0] = f2s(v[j].x * bf[j].x);
                uu[1] = f2s(v[j].y * bf[j].y);
                uu[2] = f2s(v[j].z * bf[j].z);
                uu[3] = f2s(v[j].w * bf[j].w);
#pragma unroll
                for (int c = 0; c < 4; ++c) {
                    const bool m = (uu[c] == T);
                    const unsigned long long mk = __ballot(m);
                    if (mk) {
                        const int leader = __builtin_ctzll(mk);
                        uint32_t base = 0;
                        if (lane == leader)
                            base = atomicAdd(&sh[4], (uint32_t)__builtin_popcountll(mk));
                        base = __shfl(base, leader);
                        if (m) {
                            const uint32_t p = base + (uint32_t)__builtin_popcountll(
                                                          mk & ((1ull << lane) - 1ull));
                            if (p < EQCAP)
                                eq_i[p] = (uint32_t)(4 * (j * TPB + t) + c);
                        }
                    }
                }
            }
            __syncthreads();
            if (t == 0) { // keep lowest indices first (top_k stable tie-break)
                uint32_t m2 = sh[4];
                if (m2 > EQCAP) m2 = EQCAP;
                for (uint32_t i = 1; i < m2; ++i) {
                    const uint32_t key = eq_i[i];
                    int jj = (int)i - 1;
                    while (jj >= 0 && eq_i[jj] > key) { eq_i[jj + 1] = eq_i[jj]; --jj; }
                    eq_i[jj + 1] = key;
                }
            }
            __syncthreads();
        }

        // epilogue: recompute keys, compare vs T, write output, count positives
        ((uintx4*)hist[1])[t] = z4; // restore clean-hist invariant for next row
        floatx4* o4 = (floatx4*)(out + (size_t)row * NF);
#pragma unroll
        for (int j = 0; j < 8; ++j) {
            const int idx = j * TPB + t;
            const floatx4 xv = v[j];
            const uint32_t u0 = f2s(xv.x * bf[j].x);
            const uint32_t u1 = f2s(xv.y * bf[j].y);
            const uint32_t u2 = f2s(xv.z * bf[j].z);
            const uint32_t u3 = f2s(xv.w * bf[j].w);
            const bool k0 = kept2(u0, T, (uint32_t)(4 * idx + 0), keepall, needc, eq_i);
            const bool k1 = kept2(u1, T, (uint32_t)(4 * idx + 1), keepall, needc, eq_i);
            const bool k2 = kept2(u2, T, (uint32_t)(4 * idx + 2), keepall, needc, eq_i);
            const bool k3 = kept2(u3, T, (uint32_t)(4 * idx + 3), keepall, needc, eq_i);
            floatx4 res;
            res.x = k0 ? xv.x : 0.0f;
            res.y = k1 ? xv.y : 0.0f;
            res.z = k2 ? xv.z : 0.0f;
            res.w = k3 ? xv.w : 0.0f;
            __builtin_nontemporal_store(res, &o4[idx]);
            uint32_t add = 0;
            add += (k0 && xv.x > 0.0f) ? (1u << (16 * (j & 1) + 0)) : 0u;
            add += (k1 && xv.y > 0.0f) ? (1u << (16 * (j & 1) + 4)) : 0u;
            add += (k2 && xv.z > 0.0f) ? (1u << (16 * (j & 1) + 8)) : 0u;
            add += (k3 && xv.w > 0.0f) ? (1u << (16 * (j & 1) + 12)) : 0u;
            cnt4[j >> 1] += add; // per-nibble max RPB=4, no overflow
        }
    }

    // nibble-packed per-block column counts -> workspace (coalesced, no atomics)
    {
        uint32_t* pb = partials + (size_t)blockIdx.x * (NF / 8);
#pragma unroll
        for (int jp = 0; jp < 4; ++jp) pb[jp * TPB + t] = cnt4[jp];
    }
}

// stage A: sum 16 nibble-packed block words -> byte-packed (max 16*4=64) — 128 blocks
__global__ __launch_bounds__(TPB) void redA_k(const uint32_t* __restrict__ partials,
                                              uint32_t* __restrict__ p2) {
    const int s = blockIdx.x; // 0..127
#pragma unroll
    for (int k2 = 0; k2 < 4; ++k2) {
        const int w = k2 * TPB + threadIdx.x; // 0..1023
        uint32_t a0 = 0, a1 = 0, a2 = 0, a3 = 0, a4 = 0, a5 = 0, a6 = 0, a7 = 0;
#pragma unroll
        for (int b = 0; b < 16; ++b) {
            const uint32_t p = partials[(size_t)(s * 16 + b) * 1024 + w];
            a0 += p & 0xFu;         a1 += (p >> 4) & 0xFu;
            a2 += (p >> 8) & 0xFu;  a3 += (p >> 12) & 0xFu;
            a4 += (p >> 16) & 0xFu; a5 += (p >> 20) & 0xFu;
            a6 += (p >> 24) & 0xFu; a7 += p >> 28;
        }
        p2[(size_t)s * 2048 + 2 * w]     = a0 | (a1 << 8) | (a2 << 16) | (a3 << 24);
        p2[(size_t)s * 2048 + 2 * w + 1] = a4 | (a5 << 8) | (a6 << 16) | (a7 << 24);
    }
}

// stage B: sum 128 byte-packed slices, unpack, finish EMA — 8 blocks
__global__ __launch_bounds__(TPB) void redB_k(const uint32_t* __restrict__ p2,
                                              const float* __restrict__ dc,
                                              float* __restrict__ dcout) {
    const int W = blockIdx.x * TPB + threadIdx.x; // 0..2047
    uint32_t s0 = 0, s1 = 0, s2 = 0, s3 = 0;
#pragma unroll 8
    for (int g = 0; g < 128; ++g) {
        const uint32_t p = p2[(size_t)g * 2048 + W];
        s0 += p & 0xFFu;
        s1 += (p >> 8) & 0xFFu;
        s2 += (p >> 16) & 0xFFu;
        s3 += p >> 24;
    }
    // word W = 2*w + h; w = jp*256+tt; columns 4*((2*jp+h)*256+tt) + 0..3
    const int w = W >> 1, h = W & 1;
    const int jp = w >> 8, tt = w & 255;
    const int idx4 = (2 * jp + h) * 256 + tt;
    const floatx4 d = ((const floatx4*)dc)[idx4];
    floatx4 rr;
    rr.x = 0.9f * d.x + 0.1f * (float)s0;
    rr.y = 0.9f * d.y + 0.1f * (float)s1;
    rr.z = 0.9f * d.z + 0.1f * (float)s2;
    rr.w = 0.9f * d.w + 0.1f * (float)s3;
    ((floatx4*)dcout)[idx4] = rr;
}

extern "C" void kernel_launch(void* const* d_in, const int* in_sizes, int n_in,
                              void* d_out, int out_size, void* d_ws, size_t ws_size,
                              hipStream_t stream) {
    (void)in_sizes; (void)n_in; (void)out_size; (void)ws_size;
    const float* x  = (const float*)d_in[0];
    const float* dc = (const float*)d_in[1];
    float* out   = (float*)d_out;
    float* dcout = out + (size_t)NR * NF;

    char* ws = (char*)d_ws;
    float*    boost    = (float*)ws;                    // 32 KB @ 0
    uint32_t* partials = (uint32_t*)(ws + (1u << 20));  // 8 MB  @ 1 MB  (2048 x 1024 words)
    uint32_t* p2       = (uint32_t*)(ws + (9u << 20));  // 1 MB  @ 9 MB  (128 x 2048 words)

    boost_k<<<dim3(NF / TPB), dim3(TPB), 0, stream>>>(dc, boost);
    topk_k<<<dim3(TGRID), dim3(TPB), 0, stream>>>(x, boost, out, partials);
    redA_k<<<dim3(128), dim3(TPB), 0, stream>>>(partials, p2);
    redB_k<<<dim3(8), dim3(TPB), 0, stream>>>(p2, dc, dcout);
}

// Round 2
// 725.566 us; speedup vs baseline: 1.1667x; 1.1667x over previous
//
#include <hip/hip_runtime.h>
#include <stdint.h>

#define NF 8192          // features per row
#define NR 8192          // rows
#define TPB 256          // threads per block
#define RPB 4            // rows per block
#define TGRID (NR / RPB) // 2048 blocks = exactly 8 per CU
#define KSEL 2867        // floor(0.35 * 8192)
#define CAND_CAP 2048
#define EQCAP 128

typedef float    floatx4 __attribute__((ext_vector_type(4)));
typedef uint32_t uintx4  __attribute__((ext_vector_type(4)));

// order-preserving float -> uint mapping (ascending)
__device__ __forceinline__ uint32_t f2s(float f) {
    uint32_t u = __float_as_uint(f);
    return u ^ ((uint32_t)((int32_t)u >> 31) | 0x80000000u);
}

__global__ __launch_bounds__(TPB) void boost_k(const float* __restrict__ dc,
                                               float* __restrict__ boost) {
    const int i = blockIdx.x * TPB + threadIdx.x;
    const float target = (float)KSEL / (float)NF; // 0.3499755859375, exact in f32
    boost[i] = expf(1.5f * (target - dc[i]));
}

__device__ __forceinline__ bool kept2(uint32_t u, uint32_t T, uint32_t col,
                                      bool keepall, uint32_t need,
                                      const uint32_t* eq) {
    if (u > T) return true;
    if (u != T) return false;
    if (keepall) return true;
    for (uint32_t i = 0; i < need; ++i)
        if (eq[i] == col) return true;
    return false;
}

// wave 0 only: suffix-scan 256 bins (x4 replicated), find bucket holding rank sh[1]
__device__ __forceinline__ void select_level(const uint32_t* hb, uint32_t* sh,
                                             int lane, int shift) {
    const uintx4* h4 = (const uintx4*)hb;
    uint32_t hh[4];
    uint32_t g = 0;
#pragma unroll
    for (int b = 0; b < 4; ++b) {
        const uintx4 q = h4[4 * lane + b]; // 4 replicas of bin 4*lane+b
        hh[b] = q.x + q.y + q.z + q.w;
        g += hh[b];
    }
    uint32_t inc = g;
#pragma unroll
    for (int off = 1; off < 64; off <<= 1) {
        const uint32_t o = __shfl_down(inc, off);
        if (lane + off < 64) inc += o;
    }
    const uint32_t kk = sh[1];
    const uint32_t above = inc - g; // elements in strictly higher bins
    if (above < kk && kk <= inc) {
        uint32_t c = above;
        const uint32_t oldp = sh[0];
#pragma unroll
        for (int b = 3; b >= 0; --b) {
            c += hh[b];
            if (c >= kk) {
                sh[0] = oldp | ((uint32_t)(4 * lane + b) << shift);
                sh[1] = kk - (c - hh[b]); // residual rank within bucket
                sh[2] = hh[b];            // bucket population
                break;
            }
        }
    }
}

// Stateless-recompute top-k: per-element data lives in L2 (regular cached loads),
// not in registers (spills) or LDS (occupancy). Keys recomputed 3x/row at ~4 VALU each.
__global__ __launch_bounds__(TPB, 8) void topk_k(const float* __restrict__ x,
                                                 const float* __restrict__ boost,
                                                 float* __restrict__ out,
                                                 uint32_t* __restrict__ partials) {
    // LDS: 8K hist (2 bufs x 256 bins x 4 replicas) + 8K cand + eq + sh ~= 17 KB -> 8 blocks/CU
    __shared__ __align__(16) uint32_t hist[2][1024];
    __shared__ __align__(16) uint32_t cand[CAND_CAP];
    __shared__ uint32_t eq_i[EQCAP];
    __shared__ uint32_t sh[8]; // 0: prefix/T, 1: rank residual, 2: bucket pop, 3: cand cnt, 4: eq cnt

    const int t = threadIdx.x;
    const int lane = t & 63;
    const int wv = t >> 6;
    const int sub = t & 3;
    const uintx4 z4 = {0u, 0u, 0u, 0u};
    const floatx4* b4 = (const floatx4*)boost;

    // both hist buffers clean at row start (invariant maintained by clears below)
    ((uintx4*)hist[0])[t] = z4;
    ((uintx4*)hist[1])[t] = z4;

    uint32_t cnt4[4] = {0, 0, 0, 0}; // nibble-packed per-column pos counts (8 cols/word)

    for (int r = 0; r < RPB; ++r) {
        const int row = blockIdx.x * RPB + r;
        const floatx4* x4 = (const floatx4*)(x + (size_t)row * NF);

        __syncthreads(); // prev-row epilogue done; hists clean
        if (t < 8) sh[t] = (t == 1) ? (uint32_t)KSEL : 0u;

        // pass 0: top-byte histogram; keys recomputed from cached x, boost
#pragma unroll
        for (int j = 0; j < 8; ++j) {
            const floatx4 xv = x4[j * TPB + t];
            const floatx4 bv = b4[j * TPB + t];
            atomicAdd(&hist[0][(f2s(xv.x * bv.x) >> 24) * 4 + sub], 1u);
            atomicAdd(&hist[0][(f2s(xv.y * bv.y) >> 24) * 4 + sub], 1u);
            atomicAdd(&hist[0][(f2s(xv.z * bv.z) >> 24) * 4 + sub], 1u);
            atomicAdd(&hist[0][(f2s(xv.w * bv.w) >> 24) * 4 + sub], 1u);
        }
        __syncthreads();

        if (wv == 0) select_level(hist[0], sh, lane, 24);
        __syncthreads();

        // compact the selected top-byte bucket (~0.9K keys expected) into cand[]
        const bool uc = (sh[2] <= (uint32_t)CAND_CAP); // exact count known: no overflow possible
        const uint32_t pfx0 = sh[0];
        if (uc) {
#pragma unroll
            for (int j = 0; j < 8; ++j) {
                const floatx4 xv = x4[j * TPB + t];
                const floatx4 bv = b4[j * TPB + t];
                uint32_t uu[4];
                uu[0] = f2s(xv.x * bv.x);
                uu[1] = f2s(xv.y * bv.y);
                uu[2] = f2s(xv.z * bv.z);
                uu[3] = f2s(xv.w * bv.w);
#pragma unroll
                for (int c = 0; c < 4; ++c) {
                    const bool m = (uu[c] & 0xFF000000u) == pfx0;
                    const unsigned long long mk = __ballot(m);
                    if (mk) { // wave-uniform
                        const int leader = __builtin_ctzll(mk);
                        uint32_t base = 0;
                        if (lane == leader)
                            base = atomicAdd(&sh[3], (uint32_t)__builtin_popcountll(mk));
                        base = __shfl(base, leader);
                        if (m)
                            cand[base + (uint32_t)__builtin_popcountll(
                                            mk & ((1ull << lane) - 1ull))] = uu[c];
                    }
                }
            }
        }
        __syncthreads();
        const uint32_t nc = sh[3];

        // 3 more radix levels over the compact list (fallback: rescan cached globals)
        for (int pass = 1; pass < 4; ++pass) {
            const int shift = 24 - 8 * pass;
            uint32_t* hb = hist[pass & 1];
            uint32_t* ho = hist[(pass & 1) ^ 1];
            ((uintx4*)ho)[t] = z4; // clear the other buffer (not read this phase)
            const uint32_t prefix = sh[0];
            const uint32_t himask = 0xFFFFFFFFu << (shift + 8);
            if (uc) {
                for (uint32_t i = t; i < nc; i += TPB) {
                    const uint32_t u = cand[i];
                    if ((u & himask) == prefix)
                        atomicAdd(&hb[((u >> shift) & 0xFFu) * 4 + sub], 1u);
                }
            } else {
#pragma unroll
                for (int j = 0; j < 8; ++j) {
                    const floatx4 xv = x4[j * TPB + t];
                    const floatx4 bv = b4[j * TPB + t];
                    uint32_t uu[4];
                    uu[0] = f2s(xv.x * bv.x);
                    uu[1] = f2s(xv.y * bv.y);
                    uu[2] = f2s(xv.z * bv.z);
                    uu[3] = f2s(xv.w * bv.w);
#pragma unroll
                    for (int c = 0; c < 4; ++c)
                        if ((uu[c] & himask) == prefix)
                            atomicAdd(&hb[((uu[c] >> shift) & 0xFFu) * 4 + sub], 1u);
                }
            }
            __syncthreads();
            if (wv == 0) select_level(hb, sh, lane, shift);
            __syncthreads();
        }
        // sh[0] = exact k-th largest key T; sh[1] = #ties to keep; sh[2] = #elements == T

        const uint32_t T = sh[0];
        const uint32_t need = sh[1];
        const uint32_t meq = sh[2];
        const bool keepall = (meq == need);
        const uint32_t needc = (need < (uint32_t)EQCAP) ? need : (uint32_t)EQCAP;

        if (!keepall) { // rare: duplicate keys at the threshold
#pragma unroll
            for (int j = 0; j < 8; ++j) {
                const floatx4 xv = x4[j * TPB + t];
                const floatx4 bv = b4[j * TPB + t];
                uint32_t uu[4];
                uu[0] = f2s(xv.x * bv.x);
                uu[1] = f2s(xv.y * bv.y);
                uu[2] = f2s(xv.z * bv.z);
                uu[3] = f2s(xv.w * bv.w);
#pragma unroll
                for (int c = 0; c < 4; ++c) {
                    const bool m = (uu[c] == T);
                    const unsigned long long mk = __ballot(m);
                    if (mk) {
                        const int leader = __builtin_ctzll(mk);
                        uint32_t base = 0;
                        if (lane == leader)
                            base = atomicAdd(&sh[4], (uint32_t)__builtin_popcountll(mk));
                        base = __shfl(base, leader);
                        if (m) {
                            const uint32_t p = base + (uint32_t)__builtin_popcountll(
                                                          mk & ((1ull << lane) - 1ull));
                            if (p < EQCAP)
                                eq_i[p] = (uint32_t)(4 * (j * TPB + t) + c);
                        }
                    }
                }
            }
            __syncthreads();
            if (t == 0) { // keep lowest indices first (top_k stable tie-break)
                uint32_t m2 = sh[4];
                if (m2 > EQCAP) m2 = EQCAP;
                for (uint32_t i = 1; i < m2; ++i) {
                    const uint32_t key = eq_i[i];
                    int jj = (int)i - 1;
                    while (jj >= 0 && eq_i[jj] > key) { eq_i[jj + 1] = eq_i[jj]; --jj; }
                    eq_i[jj + 1] = key;
                }
            }
            __syncthreads();
        }

        // epilogue: recompute keys, compare vs T, write output, count positives
        ((uintx4*)hist[1])[t] = z4; // restore clean-hist invariant for next row
        floatx4* o4 = (floatx4*)(out + (size_t)row * NF);
#pragma unroll
        for (int j = 0; j < 8; ++j) {
            const int idx = j * TPB + t;
            const floatx4 xv = x4[idx];
            const floatx4 bv = b4[idx];
            const uint32_t u0 = f2s(xv.x * bv.x);
            const uint32_t u1 = f2s(xv.y * bv.y);
            const uint32_t u2 = f2s(xv.z * bv.z);
            const uint32_t u3 = f2s(xv.w * bv.w);
            const bool k0 = kept2(u0, T, (uint32_t)(4 * idx + 0), keepall, needc, eq_i);
            const bool k1 = kept2(u1, T, (uint32_t)(4 * idx + 1), keepall, needc, eq_i);
            const bool k2 = kept2(u2, T, (uint32_t)(4 * idx + 2), keepall, needc, eq_i);
            const bool k3 = kept2(u3, T, (uint32_t)(4 * idx + 3), keepall, needc, eq_i);
            floatx4 res;
            res.x = k0 ? xv.x : 0.0f;
            res.y = k1 ? xv.y : 0.0f;
            res.z = k2 ? xv.z : 0.0f;
            res.w = k3 ? xv.w : 0.0f;
            __builtin_nontemporal_store(res, &o4[idx]);
            uint32_t add = 0;
            add += (k0 && xv.x > 0.0f) ? (1u << (16 * (j & 1) + 0)) : 0u;
            add += (k1 && xv.y > 0.0f) ? (1u << (16 * (j & 1) + 4)) : 0u;
            add += (k2 && xv.z > 0.0f) ? (1u << (16 * (j & 1) + 8)) : 0u;
            add += (k3 && xv.w > 0.0f) ? (1u << (16 * (j & 1) + 12)) : 0u;
            cnt4[j >> 1] += add; // per-nibble max RPB=4, no overflow
        }
    }

    // nibble-packed per-block column counts -> workspace (coalesced, no atomics)
    {
        uint32_t* pb = partials + (size_t)blockIdx.x * (NF / 8);
#pragma unroll
        for (int jp = 0; jp < 4; ++jp) pb[jp * TPB + t] = cnt4[jp];
    }
}

// stage A: sum 16 nibble-packed block words -> byte-packed (max 16*4=64) — 128 blocks
__global__ __launch_bounds__(TPB) void redA_k(const uint32_t* __restrict__ partials,
                                              uint32_t* __restrict__ p2) {
    const int s = blockIdx.x; // 0..127
#pragma unroll
    for (int k2 = 0; k2 < 4; ++k2) {
        const int w = k2 * TPB + threadIdx.x; // 0..1023
        uint32_t a0 = 0, a1 = 0, a2 = 0, a3 = 0, a4 = 0, a5 = 0, a6 = 0, a7 = 0;
#pragma unroll
        for (int b = 0; b < 16; ++b) {
            const uint32_t p = partials[(size_t)(s * 16 + b) * 1024 + w];
            a0 += p & 0xFu;         a1 += (p >> 4) & 0xFu;
            a2 += (p >> 8) & 0xFu;  a3 += (p >> 12) & 0xFu;
            a4 += (p >> 16) & 0xFu; a5 += (p >> 20) & 0xFu;
            a6 += (p >> 24) & 0xFu; a7 += p >> 28;
        }
        p2[(size_t)s * 2048 + 2 * w]     = a0 | (a1 << 8) | (a2 << 16) | (a3 << 24);
        p2[(size_t)s * 2048 + 2 * w + 1] = a4 | (a5 << 8) | (a6 << 16) | (a7 << 24);
    }
}

// stage B: sum 128 byte-packed slices, unpack, finish EMA — 8 blocks
__global__ __launch_bounds__(TPB) void redB_k(const uint32_t* __restrict__ p2,
                                              const float* __restrict__ dc,
                                              float* __restrict__ dcout) {
    const int W = blockIdx.x * TPB + threadIdx.x; // 0..2047
    uint32_t s0 = 0, s1 = 0, s2 = 0, s3 = 0;
#pragma unroll 8
    for (int g = 0; g < 128; ++g) {
        const uint32_t p = p2[(size_t)g * 2048 + W];
        s0 += p & 0xFFu;
        s1 += (p >> 8) & 0xFFu;
        s2 += (p >> 16) & 0xFFu;
        s3 += p >> 24;
    }
    // word W = 2*w + h; w = jp*256+tt; columns 4*((2*jp+h)*256+tt) + 0..3
    const int w = W >> 1, h = W & 1;
    const int jp = w >> 8, tt = w & 255;
    const int idx4 = (2 * jp + h) * 256 + tt;
    const floatx4 d = ((const floatx4*)dc)[idx4];
    floatx4 rr;
    rr.x = 0.9f * d.x + 0.1f * (float)s0;
    rr.y = 0.9f * d.y + 0.1f * (float)s1;
    rr.z = 0.9f * d.z + 0.1f * (float)s2;
    rr.w = 0.9f * d.w + 0.1f * (float)s3;
    ((floatx4*)dcout)[idx4] = rr;
}

extern "C" void kernel_launch(void* const* d_in, const int* in_sizes, int n_in,
                              void* d_out, int out_size, void* d_ws, size_t ws_size,
                              hipStream_t stream) {
    (void)in_sizes; (void)n_in; (void)out_size; (void)ws_size;
    const float* x  = (const float*)d_in[0];
    const float* dc = (const float*)d_in[1];
    float* out   = (float*)d_out;
    float* dcout = out + (size_t)NR * NF;

    char* ws = (char*)d_ws;
    float*    boost    = (float*)ws;                    // 32 KB @ 0
    uint32_t* partials = (uint32_t*)(ws + (1u << 20));  // 8 MB  @ 1 MB  (2048 x 1024 words)
    uint32_t* p2       = (uint32_t*)(ws + (9u << 20));  // 1 MB  @ 9 MB  (128 x 2048 words)

    boost_k<<<dim3(NF / TPB), dim3(TPB), 0, stream>>>(dc, boost);
    topk_k<<<dim3(TGRID), dim3(TPB), 0, stream>>>(x, boost, out, partials);
    redA_k<<<dim3(128), dim3(TPB), 0, stream>>>(partials, p2);
    redB_k<<<dim3(8), dim3(TPB), 0, stream>>>(p2, dc, dcout);
}

// Round 3
// 640.016 us; speedup vs baseline: 1.3226x; 1.1337x over previous
//
#include <hip/hip_runtime.h>
#include <stdint.h>

#define NF 8192          // features per row
#define NR 8192          // rows
#define TPB 256          // threads per block
#define RPB 4            // rows per block
#define TGRID (NR / RPB) // 2048 blocks
#define KSEL 2867        // floor(0.35 * 8192)
#define CAND_CAP 2048
#define EQCAP 128

typedef float    floatx4 __attribute__((ext_vector_type(4)));
typedef uint32_t uintx4  __attribute__((ext_vector_type(4)));

// order-preserving float -> uint mapping (ascending)
__device__ __forceinline__ uint32_t f2s(float f) {
    uint32_t u = __float_as_uint(f);
    return u ^ ((uint32_t)((int32_t)u >> 31) | 0x80000000u);
}

__global__ __launch_bounds__(TPB) void boost_k(const float* __restrict__ dc,
                                               float* __restrict__ boost) {
    const int i = blockIdx.x * TPB + threadIdx.x;
    const float target = (float)KSEL / (float)NF; // 0.3499755859375, exact in f32
    boost[i] = expf(1.5f * (target - dc[i]));
}

__device__ __forceinline__ bool kept2(uint32_t u, uint32_t T, uint32_t col,
                                      bool keepall, uint32_t need,
                                      const uint32_t* eq) {
    if (u > T) return true;
    if (u != T) return false;
    if (keepall) return true;
    for (uint32_t i = 0; i < need; ++i)
        if (eq[i] == col) return true;
    return false;
}

// wave 0 only: suffix-scan 256 bins (x4 replicated), find bucket holding rank sh[1]
__device__ __forceinline__ void select_level(const uint32_t* hb, uint32_t* sh,
                                             int lane, int shift) {
    const uintx4* h4 = (const uintx4*)hb;
    uint32_t hh[4];
    uint32_t g = 0;
#pragma unroll
    for (int b = 0; b < 4; ++b) {
        const uintx4 q = h4[4 * lane + b]; // 4 replicas of bin 4*lane+b
        hh[b] = q.x + q.y + q.z + q.w;
        g += hh[b];
    }
    uint32_t inc = g;
#pragma unroll
    for (int off = 1; off < 64; off <<= 1) {
        const uint32_t o = __shfl_down(inc, off);
        if (lane + off < 64) inc += o;
    }
    const uint32_t kk = sh[1];
    const uint32_t above = inc - g; // elements in strictly higher bins
    if (above < kk && kk <= inc) {
        uint32_t c = above;
        const uint32_t oldp = sh[0];
#pragma unroll
        for (int b = 3; b >= 0; --b) {
            c += hh[b];
            if (c >= kk) {
                sh[0] = oldp | ((uint32_t)(4 * lane + b) << shift);
                sh[1] = kk - (c - hh[b]); // residual rank within bucket
                sh[2] = hh[b];            // bucket population
                break;
            }
        }
    }
}

// x lives in registers (v[8], 32 VGPR) for the whole row: single HBM read.
// boost is block-shared 32 KB -> L1/L2-resident, reloaded per phase (CSE blocked).
// Keys recomputed from (v, boost) at ~5 VALU/elem; VALU has 5x headroom.
__global__ __launch_bounds__(TPB, 6) void topk_k(const float* __restrict__ x,
                                                 const float* __restrict__ boost,
                                                 float* __restrict__ out,
                                                 uint32_t* __restrict__ partials) {
    // LDS: 8K hist (2 bufs x 256 bins x 4 replicas) + 8K cand + eq + sh ~= 17 KB
    __shared__ __align__(16) uint32_t hist[2][1024];
    __shared__ __align__(16) uint32_t cand[CAND_CAP];
    __shared__ uint32_t eq_i[EQCAP];
    __shared__ uint32_t sh[8]; // 0: prefix/T, 1: rank residual, 2: bucket pop, 3: cand cnt, 4: eq cnt

    const int t = threadIdx.x;
    const int lane = t & 63;
    const int wv = t >> 6;
    const int sub = t & 3;
    const uintx4 z4 = {0u, 0u, 0u, 0u};
    const floatx4* b4 = (const floatx4*)boost;

    // both hist buffers clean at row start (invariant maintained by clears below)
    ((uintx4*)hist[0])[t] = z4;
    ((uintx4*)hist[1])[t] = z4;

    uint32_t cnt4[4] = {0, 0, 0, 0}; // nibble-packed per-column pos counts (8 cols/word)

    for (int r = 0; r < RPB; ++r) {
        const int row = blockIdx.x * RPB + r;
        const floatx4* x4 = (const floatx4*)(x + (size_t)row * NF);

        __syncthreads(); // prev-row epilogue done; hists clean
        if (t < 8) sh[t] = (t == 1) ? (uint32_t)KSEL : 0u;

        // pass 0: single HBM read of the row into regs; top-byte histogram
        floatx4 v[8];
#pragma unroll
        for (int j = 0; j < 8; ++j)
            v[j] = __builtin_nontemporal_load(&x4[j * TPB + t]);
#pragma unroll
        for (int j = 0; j < 8; ++j) {
            const floatx4 bv = b4[j * TPB + t];
            atomicAdd(&hist[0][(f2s(v[j].x * bv.x) >> 24) * 4 + sub], 1u);
            atomicAdd(&hist[0][(f2s(v[j].y * bv.y) >> 24) * 4 + sub], 1u);
            atomicAdd(&hist[0][(f2s(v[j].z * bv.z) >> 24) * 4 + sub], 1u);
            atomicAdd(&hist[0][(f2s(v[j].w * bv.w) >> 24) * 4 + sub], 1u);
        }
        __syncthreads();

        if (wv == 0) select_level(hist[0], sh, lane, 24);
        __syncthreads();
        asm volatile("" ::: "memory"); // block bv-load CSE across phases (reg pressure)

        // compact the selected top-byte bucket into cand[] AND build level-1 hist;
        // clear hist[0] for pass 2 on the way
        ((uintx4*)hist[0])[t] = z4;
        const bool uc = (sh[2] <= (uint32_t)CAND_CAP); // exact count: no silent overflow
        const uint32_t pfx0 = sh[0];
#pragma unroll
        for (int j = 0; j < 8; ++j) {
            const floatx4 bv = b4[j * TPB + t];
            uint32_t uu[4];
            uu[0] = f2s(v[j].x * bv.x);
            uu[1] = f2s(v[j].y * bv.y);
            uu[2] = f2s(v[j].z * bv.z);
            uu[3] = f2s(v[j].w * bv.w);
#pragma unroll
            for (int c = 0; c < 4; ++c) {
                const bool m = (uu[c] & 0xFF000000u) == pfx0;
                if (m) atomicAdd(&hist[1][((uu[c] >> 16) & 0xFFu) * 4 + sub], 1u);
                if (uc) {
                    const unsigned long long mk = __ballot(m);
                    if (mk) { // wave-uniform
                        const int leader = __builtin_ctzll(mk);
                        uint32_t base = 0;
                        if (lane == leader)
                            base = atomicAdd(&sh[3], (uint32_t)__builtin_popcountll(mk));
                        base = __shfl(base, leader);
                        if (m)
                            cand[base + (uint32_t)__builtin_popcountll(
                                            mk & ((1ull << lane) - 1ull))] = uu[c];
                    }
                }
            }
        }
        __syncthreads();
        if (wv == 0) select_level(hist[1], sh, lane, 16);
        __syncthreads();
        const uint32_t nc = sh[3];

        // passes 2,3 over the compact list (fallback: rescan registers)
#pragma unroll
        for (int pass = 2; pass < 4; ++pass) {
            const int shift = 24 - 8 * pass;
            uint32_t* hb = hist[pass & 1];
            uint32_t* ho = hist[(pass & 1) ^ 1];
            ((uintx4*)ho)[t] = z4; // clear the other buffer (not read this phase)
            const uint32_t prefix = sh[0];
            const uint32_t himask = 0xFFFFFFFFu << (shift + 8);
            if (uc) {
                for (uint32_t i = t; i < nc; i += TPB) {
                    const uint32_t u = cand[i];
                    if ((u & himask) == prefix)
                        atomicAdd(&hb[((u >> shift) & 0xFFu) * 4 + sub], 1u);
                }
            } else {
                asm volatile("" ::: "memory");
#pragma unroll
                for (int j = 0; j < 8; ++j) {
                    const floatx4 bv = b4[j * TPB + t];
                    uint32_t uu[4];
                    uu[0] = f2s(v[j].x * bv.x);
                    uu[1] = f2s(v[j].y * bv.y);
                    uu[2] = f2s(v[j].z * bv.z);
                    uu[3] = f2s(v[j].w * bv.w);
#pragma unroll
                    for (int c = 0; c < 4; ++c)
                        if ((uu[c] & himask) == prefix)
                            atomicAdd(&hb[((uu[c] >> shift) & 0xFFu) * 4 + sub], 1u);
                }
            }
            __syncthreads();
            if (wv == 0) select_level(hb, sh, lane, shift);
            __syncthreads();
        }
        // sh[0] = exact k-th largest key T; sh[1] = #ties to keep; sh[2] = #elements == T

        const uint32_t T = sh[0];
        const uint32_t need = sh[1];
        const uint32_t meq = sh[2];
        const bool keepall = (meq == need);
        const uint32_t needc = (need < (uint32_t)EQCAP) ? need : (uint32_t)EQCAP;

        if (!keepall) { // rare: duplicate keys at the threshold
            asm volatile("" ::: "memory");
#pragma unroll
            for (int j = 0; j < 8; ++j) {
                const floatx4 bv = b4[j * TPB + t];
                uint32_t uu[4];
                uu[0] = f2s(v[j].x * bv.x);
                uu[1] = f2s(v[j].y * bv.y);
                uu[2] = f2s(v[j].z * bv.z);
                uu[3] = f2s(v[j].w * bv.w);
#pragma unroll
                for (int c = 0; c < 4; ++c) {
                    const bool m = (uu[c] == T);
                    const unsigned long long mk = __ballot(m);
                    if (mk) {
                        const int leader = __builtin_ctzll(mk);
                        uint32_t base = 0;
                        if (lane == leader)
                            base = atomicAdd(&sh[4], (uint32_t)__builtin_popcountll(mk));
                        base = __shfl(base, leader);
                        if (m) {
                            const uint32_t p = base + (uint32_t)__builtin_popcountll(
                                                          mk & ((1ull << lane) - 1ull));
                            if (p < EQCAP)
                                eq_i[p] = (uint32_t)(4 * (j * TPB + t) + c);
                        }
                    }
                }
            }
            __syncthreads();
            if (t == 0) { // keep lowest indices first (top_k stable tie-break)
                uint32_t m2 = sh[4];
                if (m2 > EQCAP) m2 = EQCAP;
                for (uint32_t i = 1; i < m2; ++i) {
                    const uint32_t key = eq_i[i];
                    int jj = (int)i - 1;
                    while (jj >= 0 && eq_i[jj] > key) { eq_i[jj + 1] = eq_i[jj]; --jj; }
                    eq_i[jj + 1] = key;
                }
            }
            __syncthreads();
        }

        // epilogue: recompute keys from regs, compare vs T, write output, count positives
        asm volatile("" ::: "memory");
        ((uintx4*)hist[1])[t] = z4; // restore clean-hist invariant for next row
        floatx4* o4 = (floatx4*)(out + (size_t)row * NF);
#pragma unroll
        for (int j = 0; j < 8; ++j) {
            const int idx = j * TPB + t;
            const floatx4 xv = v[j];
            const floatx4 bv = b4[idx];
            const uint32_t u0 = f2s(xv.x * bv.x);
            const uint32_t u1 = f2s(xv.y * bv.y);
            const uint32_t u2 = f2s(xv.z * bv.z);
            const uint32_t u3 = f2s(xv.w * bv.w);
            const bool k0 = kept2(u0, T, (uint32_t)(4 * idx + 0), keepall, needc, eq_i);
            const bool k1 = kept2(u1, T, (uint32_t)(4 * idx + 1), keepall, needc, eq_i);
            const bool k2 = kept2(u2, T, (uint32_t)(4 * idx + 2), keepall, needc, eq_i);
            const bool k3 = kept2(u3, T, (uint32_t)(4 * idx + 3), keepall, needc, eq_i);
            floatx4 res;
            res.x = k0 ? xv.x : 0.0f;
            res.y = k1 ? xv.y : 0.0f;
            res.z = k2 ? xv.z : 0.0f;
            res.w = k3 ? xv.w : 0.0f;
            __builtin_nontemporal_store(res, &o4[idx]);
            uint32_t add = 0;
            add += (k0 && xv.x > 0.0f) ? (1u << (16 * (j & 1) + 0)) : 0u;
            add += (k1 && xv.y > 0.0f) ? (1u << (16 * (j & 1) + 4)) : 0u;
            add += (k2 && xv.z > 0.0f) ? (1u << (16 * (j & 1) + 8)) : 0u;
            add += (k3 && xv.w > 0.0f) ? (1u << (16 * (j & 1) + 12)) : 0u;
            cnt4[j >> 1] += add; // per-nibble max RPB=4, no overflow
        }
    }

    // nibble-packed per-block column counts -> workspace (coalesced, no atomics)
    {
        uint32_t* pb = partials + (size_t)blockIdx.x * (NF / 8);
#pragma unroll
        for (int jp = 0; jp < 4; ++jp) pb[jp * TPB + t] = cnt4[jp];
    }
}

// stage A: sum 16 nibble-packed block words -> byte-packed (max 16*4=64) — 128 blocks
__global__ __launch_bounds__(TPB) void redA_k(const uint32_t* __restrict__ partials,
                                              uint32_t* __restrict__ p2) {
    const int s = blockIdx.x; // 0..127
#pragma unroll
    for (int k2 = 0; k2 < 4; ++k2) {
        const int w = k2 * TPB + threadIdx.x; // 0..1023
        uint32_t a0 = 0, a1 = 0, a2 = 0, a3 = 0, a4 = 0, a5 = 0, a6 = 0, a7 = 0;
#pragma unroll
        for (int b = 0; b < 16; ++b) {
            const uint32_t p = partials[(size_t)(s * 16 + b) * 1024 + w];
            a0 += p & 0xFu;         a1 += (p >> 4) & 0xFu;
            a2 += (p >> 8) & 0xFu;  a3 += (p >> 12) & 0xFu;
            a4 += (p >> 16) & 0xFu; a5 += (p >> 20) & 0xFu;
            a6 += (p >> 24) & 0xFu; a7 += p >> 28;
        }
        p2[(size_t)s * 2048 + 2 * w]     = a0 | (a1 << 8) | (a2 << 16) | (a3 << 24);
        p2[(size_t)s * 2048 + 2 * w + 1] = a4 | (a5 << 8) | (a6 << 16) | (a7 << 24);
    }
}

// stage B: sum 128 byte-packed slices, unpack, finish EMA — 8 blocks
__global__ __launch_bounds__(TPB) void redB_k(const uint32_t* __restrict__ p2,
                                              const float* __restrict__ dc,
                                              float* __restrict__ dcout) {
    const int W = blockIdx.x * TPB + threadIdx.x; // 0..2047
    uint32_t s0 = 0, s1 = 0, s2 = 0, s3 = 0;
#pragma unroll 8
    for (int g = 0; g < 128; ++g) {
        const uint32_t p = p2[(size_t)g * 2048 + W];
        s0 += p & 0xFFu;
        s1 += (p >> 8) & 0xFFu;
        s2 += (p >> 16) & 0xFFu;
        s3 += p >> 24;
    }
    // word W = 2*w + h; w = jp*256+tt; columns 4*((2*jp+h)*256+tt) + 0..3
    const int w = W >> 1, h = W & 1;
    const int jp = w >> 8, tt = w & 255;
    const int idx4 = (2 * jp + h) * 256 + tt;
    const floatx4 d = ((const floatx4*)dc)[idx4];
    floatx4 rr;
    rr.x = 0.9f * d.x + 0.1f * (float)s0;
    rr.y = 0.9f * d.y + 0.1f * (float)s1;
    rr.z = 0.9f * d.z + 0.1f * (float)s2;
    rr.w = 0.9f * d.w + 0.1f * (float)s3;
    ((floatx4*)dcout)[idx4] = rr;
}

extern "C" void kernel_launch(void* const* d_in, const int* in_sizes, int n_in,
                              void* d_out, int out_size, void* d_ws, size_t ws_size,
                              hipStream_t stream) {
    (void)in_sizes; (void)n_in; (void)out_size; (void)ws_size;
    const float* x  = (const float*)d_in[0];
    const float* dc = (const float*)d_in[1];
    float* out   = (float*)d_out;
    float* dcout = out + (size_t)NR * NF;

    char* ws = (char*)d_ws;
    float*    boost    = (float*)ws;                    // 32 KB @ 0
    uint32_t* partials = (uint32_t*)(ws + (1u << 20));  // 8 MB  @ 1 MB  (2048 x 1024 words)
    uint32_t* p2       = (uint32_t*)(ws + (9u << 20));  // 1 MB  @ 9 MB  (128 x 2048 words)

    boost_k<<<dim3(NF / TPB), dim3(TPB), 0, stream>>>(dc, boost);
    topk_k<<<dim3(TGRID), dim3(TPB), 0, stream>>>(x, boost, out, partials);
    redA_k<<<dim3(128), dim3(TPB), 0, stream>>>(partials, p2);
    redB_k<<<dim3(8), dim3(TPB), 0, stream>>>(p2, dc, dcout);
}

// Round 4
// 520.886 us; speedup vs baseline: 1.6251x; 1.2287x over previous
//
#include <hip/hip_runtime.h>
#include <stdint.h>

#define NF 8192          // features per row
#define NR 8192          // rows
#define TPB 256          // threads per block
#define RPB 8            // rows per block
#define TGRID (NR / RPB) // 1024 blocks = exactly 4 resident per CU
#define KSEL 2867        // floor(0.35 * 8192)
#define CAND_EFF 1016    // cand[1016..1023] aliased as sh[] scalars
#define EQCAP 128

typedef float    floatx4 __attribute__((ext_vector_type(4)));
typedef uint32_t uintx4  __attribute__((ext_vector_type(4)));

// order-preserving float -> uint mapping (ascending)
__device__ __forceinline__ uint32_t f2s(float f) {
    uint32_t u = __float_as_uint(f);
    return u ^ ((uint32_t)((int32_t)u >> 31) | 0x80000000u);
}

__global__ __launch_bounds__(TPB) void boost_k(const float* __restrict__ dc,
                                               float* __restrict__ boost) {
    const int i = blockIdx.x * TPB + threadIdx.x;
    const float target = (float)KSEL / (float)NF; // 0.3499755859375, exact in f32
    boost[i] = expf(1.5f * (target - dc[i]));
}

__device__ __forceinline__ bool kept2(uint32_t u, uint32_t T, uint32_t col,
                                      bool keepall, uint32_t need,
                                      const uint32_t* eq) {
    if (u > T) return true;
    if (u != T) return false;
    if (keepall) return true;
    for (uint32_t i = 0; i < need; ++i)
        if (eq[i] == col) return true;
    return false;
}

// wave 0: select over 1024 bins (pass 0, 10-bit). Reads its 16 words, ZEROES them
// (restores clean-hist invariant with no extra barrier), suffix-scans, finds the
// bucket containing rank sh[1]. sh lives at cand[1016..].
__device__ __forceinline__ void select10(uint32_t* hist, uint32_t* shp, int lane) {
    uintx4 q[4];
#pragma unroll
    for (int a = 0; a < 4; ++a) q[a] = ((uintx4*)hist)[4 * lane + a];
    const uintx4 z4 = {0u, 0u, 0u, 0u};
#pragma unroll
    for (int a = 0; a < 4; ++a) ((uintx4*)hist)[4 * lane + a] = z4; // zero-after-read
    uint32_t h[16];
#pragma unroll
    for (int a = 0; a < 4; ++a) {
        h[4 * a + 0] = q[a].x; h[4 * a + 1] = q[a].y;
        h[4 * a + 2] = q[a].z; h[4 * a + 3] = q[a].w;
    }
    uint32_t g = 0;
#pragma unroll
    for (int b = 0; b < 16; ++b) g += h[b];
    uint32_t inc = g;
#pragma unroll
    for (int off = 1; off < 64; off <<= 1) {
        const uint32_t o = __shfl_down(inc, off);
        if (lane + off < 64) inc += o;
    }
    const uint32_t kk = shp[1];
    const uint32_t above = inc - g; // keys in strictly higher bins
    if (above < kk && kk <= inc) {
        uint32_t c = above;
#pragma unroll
        for (int b = 15; b >= 0; --b) {
            c += h[b];
            if (c >= kk) {
                shp[0] = (uint32_t)(16 * lane + b) << 22;
                shp[1] = kk - (c - h[b]); // residual rank within bucket
                shp[2] = h[b];            // bucket population
                break;
            }
        }
    }
}

// wave 0: select over 256 bins x4 replicas (passes 1-3). Same zero-after-read.
__device__ __forceinline__ void select8(uint32_t* hist, uint32_t* shp, int lane,
                                        int shift) {
    uintx4 q[4];
#pragma unroll
    for (int a = 0; a < 4; ++a) q[a] = ((uintx4*)hist)[4 * lane + a];
    const uintx4 z4 = {0u, 0u, 0u, 0u};
#pragma unroll
    for (int a = 0; a < 4; ++a) ((uintx4*)hist)[4 * lane + a] = z4;
    uint32_t hh[4];
    uint32_t g = 0;
#pragma unroll
    for (int b = 0; b < 4; ++b) { // bin 4*lane+b = sum of its 4 replicas
        hh[b] = q[b].x + q[b].y + q[b].z + q[b].w;
        g += hh[b];
    }
    uint32_t inc = g;
#pragma unroll
    for (int off = 1; off < 64; off <<= 1) {
        const uint32_t o = __shfl_down(inc, off);
        if (lane + off < 64) inc += o;
    }
    const uint32_t kk = shp[1];
    const uint32_t above = inc - g;
    if (above < kk && kk <= inc) {
        uint32_t c = above;
        const uint32_t oldp = shp[0];
#pragma unroll
        for (int b = 3; b >= 0; --b) {
            c += hh[b];
            if (c >= kk) {
                shp[0] = oldp | ((uint32_t)(4 * lane + b) << shift);
                shp[1] = kk - (c - hh[b]);
                shp[2] = hh[b];
                break;
            }
        }
    }
}

// Row lives in LDS (su, x-bits): single HBM read + single HBM write per element.
// Keys recomputed from su x boost (L1-resident) at ~5 VALU/elem.
// Radix 10+8+8+6: pass-0 bucket = half-binade (~730 elems) -> compaction engages.
// LDS = 32768(su) + 4096(hist) + 4096(cand; sh aliased at tail, eq at head)
//     = 40960 B exactly -> 4 blocks/CU.
__global__ __launch_bounds__(TPB, 4) void topk_k(const float* __restrict__ x,
                                                 const float* __restrict__ boost,
                                                 float* __restrict__ out,
                                                 uint32_t* __restrict__ partials) {
    __shared__ __align__(16) uint32_t su[NF];     // x-bits of the current row
    __shared__ __align__(16) uint32_t hist[1024]; // p0: 1024 bins; p1-3: 256 bins x4
    __shared__ __align__(16) uint32_t cand[1024]; // [0..1015] candidates / eq alias

    uint32_t* const shp = &cand[1016]; // 0:prefix/T 1:rank 2:pop 3:cand cnt 4:eq cnt
    uint32_t* const eq  = &cand[0];    // alias: used only after radix passes done

    const int t = threadIdx.x;
    const int lane = t & 63;
    const int wv = t >> 6;
    const int sub = t & 3;
    const uintx4 z4 = {0u, 0u, 0u, 0u};
    const floatx4* b4 = (const floatx4*)boost;

    ((uintx4*)hist)[t] = z4; // clean-hist invariant at row start

    uint32_t cnt4[4] = {0, 0, 0, 0}; // nibble-packed per-column pos counts (8 cols/word)

    for (int r = 0; r < RPB; ++r) {
        const int row = blockIdx.x * RPB + r;
        const floatx4* x4 = (const floatx4*)(x + (size_t)row * NF);

        __syncthreads(); // prev-row epilogue (su readers) done; hist clean
        if (t < 8) shp[t] = (t == 1) ? (uint32_t)KSEL : 0u;

        // stage: x -> su (one HBM read); 10-bit top histogram
#pragma unroll
        for (int j = 0; j < 8; ++j) {
            const int idx = j * TPB + t;
            const floatx4 xv = __builtin_nontemporal_load(&x4[idx]);
            ((floatx4*)su)[idx] = xv;
            const floatx4 bv = b4[idx];
            atomicAdd(&hist[f2s(xv.x * bv.x) >> 22], 1u);
            atomicAdd(&hist[f2s(xv.y * bv.y) >> 22], 1u);
            atomicAdd(&hist[f2s(xv.z * bv.z) >> 22], 1u);
            atomicAdd(&hist[f2s(xv.w * bv.w) >> 22], 1u);
        }
        __syncthreads();
        if (wv == 0) select10(hist, shp, lane);
        __syncthreads();

        // compact the selected bucket into cand[] AND build pass-1 hist (bits 21:14)
        const uint32_t pfx0 = shp[0];
        const bool uc = (shp[2] <= (uint32_t)CAND_EFF); // exact pop known: safe gate
#pragma unroll
        for (int j = 0; j < 8; ++j) {
            const int idx = j * TPB + t;
            const floatx4 xv = ((const floatx4*)su)[idx];
            const floatx4 bv = b4[idx];
            uint32_t uu[4];
            uu[0] = f2s(xv.x * bv.x);
            uu[1] = f2s(xv.y * bv.y);
            uu[2] = f2s(xv.z * bv.z);
            uu[3] = f2s(xv.w * bv.w);
#pragma unroll
            for (int c = 0; c < 4; ++c) {
                const bool m = (uu[c] & 0xFFC00000u) == pfx0;
                if (m) atomicAdd(&hist[((uu[c] >> 14) & 0xFFu) * 4 + sub], 1u);
                if (uc) {
                    const unsigned long long mk = __ballot(m);
                    if (mk) { // wave-uniform
                        const int leader = __builtin_ctzll(mk);
                        uint32_t base = 0;
                        if (lane == leader)
                            base = atomicAdd(&shp[3], (uint32_t)__builtin_popcountll(mk));
                        base = __shfl(base, leader);
                        if (m)
                            cand[base + (uint32_t)__builtin_popcountll(
                                            mk & ((1ull << lane) - 1ull))] = uu[c];
                    }
                }
            }
        }
        __syncthreads();
        if (wv == 0) select8(hist, shp, lane, 14);
        __syncthreads();
        const uint32_t nc = shp[3];

        // passes 2 (bits 13:6) and 3 (bits 5:0) over the compact list
#pragma unroll
        for (int pass = 2; pass < 4; ++pass) {
            const int shift = (pass == 2) ? 6 : 0;
            const uint32_t himask = (pass == 2) ? 0xFFFFC000u : 0xFFFFFFC0u;
            const uint32_t bmask = (pass == 2) ? 0xFFu : 0x3Fu;
            const uint32_t prefix = shp[0];
            if (uc) {
                for (uint32_t i = t; i < nc; i += TPB) {
                    const uint32_t u = cand[i];
                    if ((u & himask) == prefix)
                        atomicAdd(&hist[((u >> shift) & bmask) * 4 + sub], 1u);
                }
            } else { // fallback: rescan su (rare)
#pragma unroll
                for (int j = 0; j < 8; ++j) {
                    const int idx = j * TPB + t;
                    const floatx4 xv = ((const floatx4*)su)[idx];
                    const floatx4 bv = b4[idx];
                    uint32_t uu[4];
                    uu[0] = f2s(xv.x * bv.x);
                    uu[1] = f2s(xv.y * bv.y);
                    uu[2] = f2s(xv.z * bv.z);
                    uu[3] = f2s(xv.w * bv.w);
#pragma unroll
                    for (int c = 0; c < 4; ++c)
                        if ((uu[c] & himask) == prefix)
                            atomicAdd(&hist[((uu[c] >> shift) & bmask) * 4 + sub], 1u);
                }
            }
            __syncthreads();
            if (wv == 0) select8(hist, shp, lane, shift);
            __syncthreads();
        }
        // shp[0] = exact k-th largest key T; shp[1] = #ties to keep; shp[2] = #(key==T)

        const uint32_t T = shp[0];
        const uint32_t need = shp[1];
        const bool keepall = (shp[2] == need);
        const uint32_t needc = (need < (uint32_t)EQCAP) ? need : (uint32_t)EQCAP;

        if (!keepall) { // rare: duplicate keys at the threshold; collect tie columns
#pragma unroll
            for (int j = 0; j < 8; ++j) {
                const int idx = j * TPB + t;
                const floatx4 xv = ((const floatx4*)su)[idx];
                const floatx4 bv = b4[idx];
                uint32_t uu[4];
                uu[0] = f2s(xv.x * bv.x);
                uu[1] = f2s(xv.y * bv.y);
                uu[2] = f2s(xv.z * bv.z);
                uu[3] = f2s(xv.w * bv.w);
#pragma unroll
                for (int c = 0; c < 4; ++c) {
                    if (uu[c] == T) {
                        const uint32_t p = atomicAdd(&shp[4], 1u);
                        if (p < EQCAP) eq[p] = (uint32_t)(4 * idx + c);
                    }
                }
            }
            __syncthreads();
            if (t == 0) { // keep lowest indices first (top_k stable tie-break)
                uint32_t m2 = shp[4];
                if (m2 > EQCAP) m2 = EQCAP;
                for (uint32_t i = 1; i < m2; ++i) {
                    const uint32_t key = eq[i];
                    int jj = (int)i - 1;
                    while (jj >= 0 && eq[jj] > key) { eq[jj + 1] = eq[jj]; --jj; }
                    eq[jj + 1] = key;
                }
            }
            __syncthreads();
        }

        // epilogue: read su, recompute keys, compare vs T, write out, count positives
        floatx4* o4 = (floatx4*)(out + (size_t)row * NF);
#pragma unroll
        for (int j = 0; j < 8; ++j) {
            const int idx = j * TPB + t;
            const floatx4 xv = ((const floatx4*)su)[idx];
            const floatx4 bv = b4[idx];
            const uint32_t u0 = f2s(xv.x * bv.x);
            const uint32_t u1 = f2s(xv.y * bv.y);
            const uint32_t u2 = f2s(xv.z * bv.z);
            const uint32_t u3 = f2s(xv.w * bv.w);
            const bool k0 = kept2(u0, T, (uint32_t)(4 * idx + 0), keepall, needc, eq);
            const bool k1 = kept2(u1, T, (uint32_t)(4 * idx + 1), keepall, needc, eq);
            const bool k2 = kept2(u2, T, (uint32_t)(4 * idx + 2), keepall, needc, eq);
            const bool k3 = kept2(u3, T, (uint32_t)(4 * idx + 3), keepall, needc, eq);
            floatx4 res;
            res.x = k0 ? xv.x : 0.0f;
            res.y = k1 ? xv.y : 0.0f;
            res.z = k2 ? xv.z : 0.0f;
            res.w = k3 ? xv.w : 0.0f;
            __builtin_nontemporal_store(res, &o4[idx]);
            uint32_t add = 0;
            add += (k0 && xv.x > 0.0f) ? (1u << (16 * (j & 1) + 0)) : 0u;
            add += (k1 && xv.y > 0.0f) ? (1u << (16 * (j & 1) + 4)) : 0u;
            add += (k2 && xv.z > 0.0f) ? (1u << (16 * (j & 1) + 8)) : 0u;
            add += (k3 && xv.w > 0.0f) ? (1u << (16 * (j & 1) + 12)) : 0u;
            cnt4[j >> 1] += add; // per-nibble max RPB=8 < 16, no overflow
        }
    }

    // nibble-packed per-block column counts -> workspace (coalesced, no atomics)
    {
        uint32_t* pb = partials + (size_t)blockIdx.x * (NF / 8);
#pragma unroll
        for (int jp = 0; jp < 4; ++jp) pb[jp * TPB + t] = cnt4[jp];
    }
}

// stage A: sum 16 nibble-packed block words -> byte-packed (max 16*8=128) — 64 blocks
__global__ __launch_bounds__(TPB) void redA_k(const uint32_t* __restrict__ partials,
                                              uint32_t* __restrict__ p2) {
    const int s = blockIdx.x; // 0..63
#pragma unroll
    for (int k2 = 0; k2 < 4; ++k2) {
        const int w = k2 * TPB + threadIdx.x; // 0..1023
        uint32_t a0 = 0, a1 = 0, a2 = 0, a3 = 0, a4 = 0, a5 = 0, a6 = 0, a7 = 0;
#pragma unroll
        for (int b = 0; b < 16; ++b) {
            const uint32_t p = partials[(size_t)(s * 16 + b) * 1024 + w];
            a0 += p & 0xFu;         a1 += (p >> 4) & 0xFu;
            a2 += (p >> 8) & 0xFu;  a3 += (p >> 12) & 0xFu;
            a4 += (p >> 16) & 0xFu; a5 += (p >> 20) & 0xFu;
            a6 += (p >> 24) & 0xFu; a7 += p >> 28;
        }
        p2[(size_t)s * 2048 + 2 * w]     = a0 | (a1 << 8) | (a2 << 16) | (a3 << 24);
        p2[(size_t)s * 2048 + 2 * w + 1] = a4 | (a5 << 8) | (a6 << 16) | (a7 << 24);
    }
}

// stage B: sum 64 byte-packed slices, unpack, finish EMA — 8 blocks
__global__ __launch_bounds__(TPB) void redB_k(const uint32_t* __restrict__ p2,
                                              const float* __restrict__ dc,
                                              float* __restrict__ dcout) {
    const int W = blockIdx.x * TPB + threadIdx.x; // 0..2047
    uint32_t s0 = 0, s1 = 0, s2 = 0, s3 = 0;
#pragma unroll 8
    for (int g = 0; g < 64; ++g) {
        const uint32_t p = p2[(size_t)g * 2048 + W];
        s0 += p & 0xFFu;
        s1 += (p >> 8) & 0xFFu;
        s2 += (p >> 16) & 0xFFu;
        s3 += p >> 24;
    }
    // word W = 2*w + h; w = jp*256+tt; columns 4*((2*jp+h)*256+tt) + 0..3
    const int w = W >> 1, h = W & 1;
    const int jp = w >> 8, tt = w & 255;
    const int idx4 = (2 * jp + h) * 256 + tt;
    const floatx4 d = ((const floatx4*)dc)[idx4];
    floatx4 rr;
    rr.x = 0.9f * d.x + 0.1f * (float)s0;
    rr.y = 0.9f * d.y + 0.1f * (float)s1;
    rr.z = 0.9f * d.z + 0.1f * (float)s2;
    rr.w = 0.9f * d.w + 0.1f * (float)s3;
    ((floatx4*)dcout)[idx4] = rr;
}

extern "C" void kernel_launch(void* const* d_in, const int* in_sizes, int n_in,
                              void* d_out, int out_size, void* d_ws, size_t ws_size,
                              hipStream_t stream) {
    (void)in_sizes; (void)n_in; (void)out_size; (void)ws_size;
    const float* x  = (const float*)d_in[0];
    const float* dc = (const float*)d_in[1];
    float* out   = (float*)d_out;
    float* dcout = out + (size_t)NR * NF;

    char* ws = (char*)d_ws;
    float*    boost    = (float*)ws;                    // 32 KB @ 0
    uint32_t* partials = (uint32_t*)(ws + (1u << 20));  // 4 MB  @ 1 MB  (1024 x 1024 words)
    uint32_t* p2       = (uint32_t*)(ws + (9u << 20));  // 512 KB @ 9 MB (64 x 2048 words)

    boost_k<<<dim3(NF / TPB), dim3(TPB), 0, stream>>>(dc, boost);
    topk_k<<<dim3(TGRID), dim3(TPB), 0, stream>>>(x, boost, out, partials);
    redA_k<<<dim3(64), dim3(TPB), 0, stream>>>(partials, p2);
    redB_k<<<dim3(8), dim3(TPB), 0, stream>>>(p2, dc, dcout);
}